// Round 7
// baseline (429.728 us; speedup 1.0000x reference)
//
#include <hip/hip_runtime.h>

#define NN 50000
#define NE 800000
#define NQ 200000
#define NC 86
#define CAP 64

typedef short short8 __attribute__((ext_vector_type(8)));
typedef float f32x4 __attribute__((ext_vector_type(4)));
typedef unsigned short us4 __attribute__((ext_vector_type(4)));

__device__ __forceinline__ unsigned short f2bf(float f) {
    unsigned u = __float_as_uint(f);
    u += 0x7FFF + ((u >> 16) & 1);  // round-to-nearest-even
    return (unsigned short)(u >> 16);
}
__device__ __forceinline__ float bf_lo(unsigned p) { return __uint_as_float(p << 16); }
__device__ __forceinline__ float bf_hi(unsigned p) { return __uint_as_float(p & 0xffff0000u); }

// ---------------- CSR build: slot[dst][p] = src (atomic append) ----------------
__global__ __launch_bounds__(256) void k_fill(const int* __restrict__ src,
                                              const int* __restrict__ dst,
                                              int* __restrict__ cnt,
                                              unsigned short* __restrict__ slot) {
    int e = blockIdx.x * 256 + threadIdx.x;
    if (e >= NE) return;
    int d = dst[e];
    int p = atomicAdd(&cnt[d], 1);
    if (p < CAP) slot[(size_t)d * CAP + p] = (unsigned short)src[e];
}

__global__ __launch_bounds__(256) void k_dis(const int* __restrict__ cnt,
                                             float* __restrict__ dis) {
    int n = blockIdx.x * 256 + threadIdx.x;
    if (n < NN) dis[n] = rsqrtf((float)cnt[n] + 1.0f);
}

// ---------------- weight prep: bf16, col-major (W^T) for decode ----------------
__global__ __launch_bounds__(256) void k_prep(const float* __restrict__ dW1,
                                              const float* __restrict__ dW2,
                                              unsigned short* __restrict__ W1t,
                                              unsigned short* __restrict__ W2t) {
    int i = blockIdx.x * 256 + threadIdx.x;
    if (i < 128 * 256) {  // W1t[col][k] = dW1[k][col]
        int c = i >> 8, k = i & 255;
        W1t[c * 256 + k] = f2bf(dW1[k * 128 + c]);
    }
    if (i < 96 * 128) {   // W2t[col][k] = dW2[k][col], cols padded 86->96
        int c = i >> 7, k = i & 127;
        W2t[c * 128 + k] = (c < NC) ? f2bf(dW2[k * NC + c]) : (unsigned short)0;
    }
}

// ------- X @ W (fp32 VALU, W streamed from L1/L2), out bf16. X fp32 or bf16 -------
template <bool GATHER, bool BF16IN>
__global__ __launch_bounds__(256) void k_linear(const void* __restrict__ Xv,
                                                const int* __restrict__ xidx,
                                                const float* __restrict__ W,
                                                unsigned short* __restrict__ out,
                                                int nrows) {
    __shared__ float Xl[64 * 128];  // 32 KB
    const int t = threadIdx.x;
    const int r0 = blockIdx.x * 64;

    for (int i = t; i < 2048; i += 256) {  // 64 rows x 32 float4-granules
        int row = i >> 5, c4 = i & 31;
        int gr = r0 + row;
        float4 v = make_float4(0.f, 0.f, 0.f, 0.f);
        if (gr < nrows) {
            int sr = GATHER ? xidx[gr] : gr;
            if (BF16IN) {
                const unsigned* p = (const unsigned*)Xv + (size_t)sr * 64 + c4 * 2;
                unsigned u0 = p[0], u1 = p[1];
                v.x = bf_lo(u0); v.y = bf_hi(u0);
                v.z = bf_lo(u1); v.w = bf_hi(u1);
            } else {
                v = ((const float4*)((const float*)Xv + (size_t)sr * 128))[c4];
            }
        }
        ((float4*)Xl)[i] = v;
    }
    __syncthreads();

    const int tx = t & 31;
    const int ty = t >> 5;
    float4 acc[8];
#pragma unroll
    for (int q = 0; q < 8; ++q) acc[q] = make_float4(0.f, 0.f, 0.f, 0.f);

    const float* xr = Xl + ty * 8 * 128;
    for (int k = 0; k < 128; k += 4) {
        float4 w0 = ((const float4*)(W + (size_t)(k + 0) * 128))[tx];
        float4 w1 = ((const float4*)(W + (size_t)(k + 1) * 128))[tx];
        float4 w2 = ((const float4*)(W + (size_t)(k + 2) * 128))[tx];
        float4 w3 = ((const float4*)(W + (size_t)(k + 3) * 128))[tx];
#pragma unroll
        for (int q = 0; q < 8; ++q) {
            float4 xv = *((const float4*)(xr + q * 128 + k));
            acc[q].x = fmaf(xv.x, w0.x, acc[q].x); acc[q].y = fmaf(xv.x, w0.y, acc[q].y);
            acc[q].z = fmaf(xv.x, w0.z, acc[q].z); acc[q].w = fmaf(xv.x, w0.w, acc[q].w);
            acc[q].x = fmaf(xv.y, w1.x, acc[q].x); acc[q].y = fmaf(xv.y, w1.y, acc[q].y);
            acc[q].z = fmaf(xv.y, w1.z, acc[q].z); acc[q].w = fmaf(xv.y, w1.w, acc[q].w);
            acc[q].x = fmaf(xv.z, w2.x, acc[q].x); acc[q].y = fmaf(xv.z, w2.y, acc[q].y);
            acc[q].z = fmaf(xv.z, w2.z, acc[q].z); acc[q].w = fmaf(xv.z, w2.w, acc[q].w);
            acc[q].x = fmaf(xv.w, w3.x, acc[q].x); acc[q].y = fmaf(xv.w, w3.y, acc[q].y);
            acc[q].z = fmaf(xv.w, w3.z, acc[q].z); acc[q].w = fmaf(xv.w, w3.w, acc[q].w);
        }
    }

#pragma unroll
    for (int q = 0; q < 8; ++q) {
        int gr = r0 + ty * 8 + q;
        if (gr < nrows) {
            us4 o;
            o[0] = f2bf(acc[q].x); o[1] = f2bf(acc[q].y);
            o[2] = f2bf(acc[q].z); o[3] = f2bf(acc[q].w);
            *(us4*)(out + (size_t)gr * 128 + tx * 4) = o;
        }
    }
}

// ---- pull aggregation (bf16 gather, fp32 acc) + self-loop + bias [+relu], bf16 out ----
template <bool RELU>
__global__ __launch_bounds__(256) void k_agg(const int* __restrict__ cnt,
                                             const unsigned short* __restrict__ slot,
                                             const float* __restrict__ dis,
                                             const unsigned* __restrict__ hW,   // bf16x2 rows
                                             const float* __restrict__ b,
                                             unsigned* __restrict__ out) {      // bf16x2 rows
    int n = blockIdx.x * 4 + (threadIdx.x >> 6);
    int lane = threadIdx.x & 63;
    if (n >= NN) return;
    int c = cnt[n];
    if (c > CAP) c = CAP;
    float dn = dis[n];
    const unsigned short* sl = slot + (size_t)n * CAP;
    float a0 = 0.f, a1 = 0.f;
    int j = 0;
    for (; j + 7 < c; j += 8) {  // 8 gathers in flight
        us4 sa = *(const us4*)(sl + j);
        us4 sb = *(const us4*)(sl + j + 4);
        int s0 = sa[0], s1 = sa[1], s2 = sa[2], s3 = sa[3];
        int s4 = sb[0], s5 = sb[1], s6 = sb[2], s7 = sb[3];
        unsigned p0 = hW[(size_t)s0 * 64 + lane];
        unsigned p1 = hW[(size_t)s1 * 64 + lane];
        unsigned p2 = hW[(size_t)s2 * 64 + lane];
        unsigned p3 = hW[(size_t)s3 * 64 + lane];
        unsigned p4 = hW[(size_t)s4 * 64 + lane];
        unsigned p5 = hW[(size_t)s5 * 64 + lane];
        unsigned p6 = hW[(size_t)s6 * 64 + lane];
        unsigned p7 = hW[(size_t)s7 * 64 + lane];
        float nm0 = dn * dis[s0], nm1 = dn * dis[s1];
        float nm2 = dn * dis[s2], nm3 = dn * dis[s3];
        float nm4 = dn * dis[s4], nm5 = dn * dis[s5];
        float nm6 = dn * dis[s6], nm7 = dn * dis[s7];
        a0 = fmaf(bf_lo(p0), nm0, a0); a1 = fmaf(bf_hi(p0), nm0, a1);
        a0 = fmaf(bf_lo(p1), nm1, a0); a1 = fmaf(bf_hi(p1), nm1, a1);
        a0 = fmaf(bf_lo(p2), nm2, a0); a1 = fmaf(bf_hi(p2), nm2, a1);
        a0 = fmaf(bf_lo(p3), nm3, a0); a1 = fmaf(bf_hi(p3), nm3, a1);
        a0 = fmaf(bf_lo(p4), nm4, a0); a1 = fmaf(bf_hi(p4), nm4, a1);
        a0 = fmaf(bf_lo(p5), nm5, a0); a1 = fmaf(bf_hi(p5), nm5, a1);
        a0 = fmaf(bf_lo(p6), nm6, a0); a1 = fmaf(bf_hi(p6), nm6, a1);
        a0 = fmaf(bf_lo(p7), nm7, a0); a1 = fmaf(bf_hi(p7), nm7, a1);
    }
    for (; j + 3 < c; j += 4) {
        us4 sa = *(const us4*)(sl + j);
        int s0 = sa[0], s1 = sa[1], s2 = sa[2], s3 = sa[3];
        unsigned p0 = hW[(size_t)s0 * 64 + lane];
        unsigned p1 = hW[(size_t)s1 * 64 + lane];
        unsigned p2 = hW[(size_t)s2 * 64 + lane];
        unsigned p3 = hW[(size_t)s3 * 64 + lane];
        float nm0 = dn * dis[s0], nm1 = dn * dis[s1];
        float nm2 = dn * dis[s2], nm3 = dn * dis[s3];
        a0 = fmaf(bf_lo(p0), nm0, a0); a1 = fmaf(bf_hi(p0), nm0, a1);
        a0 = fmaf(bf_lo(p1), nm1, a0); a1 = fmaf(bf_hi(p1), nm1, a1);
        a0 = fmaf(bf_lo(p2), nm2, a0); a1 = fmaf(bf_hi(p2), nm2, a1);
        a0 = fmaf(bf_lo(p3), nm3, a0); a1 = fmaf(bf_hi(p3), nm3, a1);
    }
    for (; j < c; ++j) {
        int s0 = sl[j];
        unsigned p0 = hW[(size_t)s0 * 64 + lane];
        float nm0 = dn * dis[s0];
        a0 = fmaf(bf_lo(p0), nm0, a0); a1 = fmaf(bf_hi(p0), nm0, a1);
    }
    unsigned pn = hW[(size_t)n * 64 + lane];
    float r0 = fmaf(bf_lo(pn), dn * dn, a0) + b[2 * lane];
    float r1 = fmaf(bf_hi(pn), dn * dn, a1) + b[2 * lane + 1];
    if (RELU) {
        r0 = fmaxf(r0, 0.f);
        r1 = fmaxf(r1, 0.f);
    }
    out[(size_t)n * 64 + lane] = (unsigned)f2bf(r0) | ((unsigned)f2bf(r1) << 16);
}

// ---- decode: barrier-free. Each wave owns 16 queries; A-fragments gathered
// ---- directly from z; H bounced through a private per-wave LDS slice;
// ---- stage 2 computed transposed (OUT^T = W2^T * H^T) for float2 stores.
__global__ __launch_bounds__(256) void k_decode(const int* __restrict__ eli,
                                                const unsigned short* __restrict__ z,
                                                const unsigned short* __restrict__ W1t,
                                                const float* __restrict__ db1,
                                                const unsigned short* __restrict__ W2t,
                                                const float* __restrict__ db2,
                                                float* __restrict__ out) {
    __shared__ short Hs[4][16][128];  // 16 KB, per-wave private slice
    const int t = threadIdx.x;
    const int w = t >> 6;
    const int lane = t & 63;
    const int lr = lane & 15;
    const int lk = lane >> 4;
    const int qbase = blockIdx.x * 64 + w * 16;

    const int u = eli[qbase + lr];
    const int v = eli[qbase + lr + NQ];

    // prefetch all 8 A-fragments of this lane's query row: [z_u | z_v]
    short8 a[8];
#pragma unroll
    for (int ks = 0; ks < 8; ++ks) {
        int node = (ks < 4) ? u : v;
        int k8 = ks * 4 + lk;  // granule index, global k = k8*8 + i
        a[ks] = *(const short8*)(z + (size_t)node * 128 + (k8 & 15) * 8);
    }

    // stage 1: H = relu(F @ dW1 + db1), queries = A-rows, full 128 cols per wave
    f32x4 acc[8];
#pragma unroll
    for (int i = 0; i < 8; ++i) acc[i] = (f32x4){0.f, 0.f, 0.f, 0.f};
#pragma unroll
    for (int ks = 0; ks < 8; ++ks) {
        int k8 = ks * 4 + lk;
#pragma unroll
        for (int ct = 0; ct < 8; ++ct) {
            int col = ct * 16 + lr;
            short8 b = *(const short8*)(W1t + col * 256 + k8 * 8);
            acc[ct] = __builtin_amdgcn_mfma_f32_16x16x32_bf16(a[ks], b, acc[ct], 0, 0, 0);
        }
    }

    // epilogue 1: bias+relu, bounce to per-wave LDS (XOR-swizzled granules)
#pragma unroll
    for (int ct = 0; ct < 8; ++ct) {
        int col = ct * 16 + lr;
        float bv = db1[col];
        int g = col >> 3, e = col & 7;
#pragma unroll
        for (int r = 0; r < 4; ++r) {
            int row = lk * 4 + r;  // query-in-tile (C: row=(lane>>4)*4+r)
            float hv = fmaxf(acc[ct][r] + bv, 0.f);
            Hs[w][row][(((g ^ row) & 15) << 3) + e] = (short)f2bf(hv);
        }
    }
    // same-wave ds_write -> ds_read: lgkmcnt ordering only, no barrier

    // stage 2 (transposed): OUT^T = (W2^T)(H^T); A = W2t rows (classes), B = H rows
    f32x4 acc2[6];
#pragma unroll
    for (int i = 0; i < 6; ++i) acc2[i] = (f32x4){0.f, 0.f, 0.f, 0.f};
#pragma unroll
    for (int ks = 0; ks < 4; ++ks) {
        int k8 = ks * 4 + lk;
        short8 hb = *(const short8*)&Hs[w][lr][((k8 ^ lr) & 15) << 3];
#pragma unroll
        for (int ct = 0; ct < 6; ++ct) {
            int cl = ct * 16 + lr;
            short8 a2 = *(const short8*)(W2t + cl * 128 + k8 * 8);
            acc2[ct] = __builtin_amdgcn_mfma_f32_16x16x32_bf16(a2, hb, acc2[ct], 0, 0, 0);
        }
    }

    // epilogue 2: lane holds OUT^T[class = ct*16 + lk*4 + r][query = lr]
    const int qq = qbase + lr;
    float* orow = out + (size_t)qq * NC;
#pragma unroll
    for (int ct = 0; ct < 6; ++ct) {
        int cbase = ct * 16 + lk * 4;
        if (cbase + 3 < NC) {
            float2 lo = {acc2[ct][0] + db2[cbase + 0], acc2[ct][1] + db2[cbase + 1]};
            float2 hi = {acc2[ct][2] + db2[cbase + 2], acc2[ct][3] + db2[cbase + 3]};
            *(float2*)(orow + cbase) = lo;
            *(float2*)(orow + cbase + 2) = hi;
        } else if (cbase < NC) {  // cbase == 84: classes 84,85
            float2 lo = {acc2[ct][0] + db2[84], acc2[ct][1] + db2[85]};
            *(float2*)(orow + cbase) = lo;
        }
    }
}

extern "C" void kernel_launch(void* const* d_in, const int* in_sizes, int n_in,
                              void* d_out, int out_size, void* d_ws, size_t ws_size,
                              hipStream_t stream) {
    const int* x = (const int*)d_in[0];
    const int* ei = (const int*)d_in[1];
    const int* eli = (const int*)d_in[2];
    const float* emb = (const float*)d_in[3];
    const float* W1 = (const float*)d_in[4];
    const float* b1 = (const float*)d_in[5];
    const float* W2 = (const float*)d_in[6];
    const float* b2 = (const float*)d_in[7];
    const float* dW1 = (const float*)d_in[8];
    const float* db1 = (const float*)d_in[9];
    const float* dW2 = (const float*)d_in[10];
    const float* db2 = (const float*)d_in[11];
    float* out = (float*)d_out;

    const int* src = ei;
    const int* dst = ei + NE;

    unsigned short* hA = (unsigned short*)d_ws;          // NN*128 bf16
    unsigned short* hB = hA + (size_t)NN * 128;          // NN*128 bf16
    int* cnt = (int*)(hB + (size_t)NN * 128);            // NN
    float* dis = (float*)(cnt + NN);                     // NN
    unsigned short* slot = (unsigned short*)(dis + NN);  // NN*CAP u16
    unsigned short* W1t = slot + (size_t)NN * CAP;       // 128*256
    unsigned short* W2t = W1t + 128 * 256;               // 96*128

    hipMemsetAsync(cnt, 0, NN * sizeof(int), stream);
    k_prep<<<128, 256, 0, stream>>>(dW1, dW2, W1t, W2t);
    k_fill<<<(NE + 255) / 256, 256, 0, stream>>>(src, dst, cnt, slot);
    k_dis<<<(NN + 255) / 256, 256, 0, stream>>>(cnt, dis);

    // layer 1: hA = emb@W1 (bf16); hB = relu(agg(hA)+b1) (bf16)
    k_linear<true, false><<<(NN + 63) / 64, 256, 0, stream>>>(emb, x, W1, hA, NN);
    k_agg<true><<<NN / 4, 256, 0, stream>>>(cnt, slot, dis, (const unsigned*)hA, b1,
                                            (unsigned*)hB);

    // layer 2: hA = hB@W2 (bf16); hB = agg(hA)+b2 = z (bf16)
    k_linear<false, true><<<(NN + 63) / 64, 256, 0, stream>>>(hB, nullptr, W2, hA, NN);
    k_agg<false><<<NN / 4, 256, 0, stream>>>(cnt, slot, dis, (const unsigned*)hA, b2,
                                             (unsigned*)hB);

    // decode
    k_decode<<<NQ / 64, 256, 0, stream>>>(eli, hB, W1t, db1, W2t, db2, out);
}

// Round 8
// 373.715 us; speedup vs baseline: 1.1499x; 1.1499x over previous
//
#include <hip/hip_runtime.h>

#define NN 50000
#define NE 800000
#define NQ 200000
#define NC 86
#define CAP 64

typedef short short8 __attribute__((ext_vector_type(8)));
typedef float f32x4 __attribute__((ext_vector_type(4)));
typedef unsigned short us4 __attribute__((ext_vector_type(4)));

__device__ __forceinline__ unsigned short f2bf(float f) {
    unsigned u = __float_as_uint(f);
    u += 0x7FFF + ((u >> 16) & 1);  // round-to-nearest-even
    return (unsigned short)(u >> 16);
}
__device__ __forceinline__ float bf_lo(unsigned p) { return __uint_as_float(p << 16); }
__device__ __forceinline__ float bf_hi(unsigned p) { return __uint_as_float(p & 0xffff0000u); }

// ---------------- CSR build: slot[dst][p] = src (atomic append) ----------------
__global__ __launch_bounds__(256) void k_fill(const int* __restrict__ src,
                                              const int* __restrict__ dst,
                                              int* __restrict__ cnt,
                                              unsigned short* __restrict__ slot) {
    int e = blockIdx.x * 256 + threadIdx.x;
    if (e >= NE) return;
    int d = dst[e];
    int p = atomicAdd(&cnt[d], 1);
    if (p < CAP) slot[(size_t)d * CAP + p] = (unsigned short)src[e];
}

__global__ __launch_bounds__(256) void k_dis(const int* __restrict__ cnt,
                                             float* __restrict__ dis) {
    int n = blockIdx.x * 256 + threadIdx.x;
    if (n < NN) dis[n] = rsqrtf((float)cnt[n] + 1.0f);
}

// ---------------- weight prep: bf16, col-major (W^T) for decode ----------------
__global__ __launch_bounds__(256) void k_prep(const float* __restrict__ dW1,
                                              const float* __restrict__ dW2,
                                              unsigned short* __restrict__ W1t,
                                              unsigned short* __restrict__ W2t) {
    int i = blockIdx.x * 256 + threadIdx.x;
    if (i < 128 * 256) {  // W1t[col][k] = dW1[k][col]
        int c = i >> 8, k = i & 255;
        W1t[c * 256 + k] = f2bf(dW1[k * 128 + c]);
    }
    if (i < 96 * 128) {   // W2t[col][k] = dW2[k][col], cols padded 86->96
        int c = i >> 7, k = i & 127;
        W2t[c * 128 + k] = (c < NC) ? f2bf(dW2[k * NC + c]) : (unsigned short)0;
    }
}

// ------- X @ W (fp32 VALU, W streamed from L1/L2), out bf16. X fp32 or bf16 -------
template <bool GATHER, bool BF16IN>
__global__ __launch_bounds__(256) void k_linear(const void* __restrict__ Xv,
                                                const int* __restrict__ xidx,
                                                const float* __restrict__ W,
                                                unsigned short* __restrict__ out,
                                                int nrows) {
    __shared__ float Xl[64 * 128];  // 32 KB
    const int t = threadIdx.x;
    const int r0 = blockIdx.x * 64;

    for (int i = t; i < 2048; i += 256) {  // 64 rows x 32 float4-granules
        int row = i >> 5, c4 = i & 31;
        int gr = r0 + row;
        float4 v = make_float4(0.f, 0.f, 0.f, 0.f);
        if (gr < nrows) {
            int sr = GATHER ? xidx[gr] : gr;
            if (BF16IN) {
                const unsigned* p = (const unsigned*)Xv + (size_t)sr * 64 + c4 * 2;
                unsigned u0 = p[0], u1 = p[1];
                v.x = bf_lo(u0); v.y = bf_hi(u0);
                v.z = bf_lo(u1); v.w = bf_hi(u1);
            } else {
                v = ((const float4*)((const float*)Xv + (size_t)sr * 128))[c4];
            }
        }
        ((float4*)Xl)[i] = v;
    }
    __syncthreads();

    const int tx = t & 31;
    const int ty = t >> 5;
    float4 acc[8];
#pragma unroll
    for (int q = 0; q < 8; ++q) acc[q] = make_float4(0.f, 0.f, 0.f, 0.f);

    const float* xr = Xl + ty * 8 * 128;
    for (int k = 0; k < 128; k += 4) {
        float4 w0 = ((const float4*)(W + (size_t)(k + 0) * 128))[tx];
        float4 w1 = ((const float4*)(W + (size_t)(k + 1) * 128))[tx];
        float4 w2 = ((const float4*)(W + (size_t)(k + 2) * 128))[tx];
        float4 w3 = ((const float4*)(W + (size_t)(k + 3) * 128))[tx];
#pragma unroll
        for (int q = 0; q < 8; ++q) {
            float4 xv = *((const float4*)(xr + q * 128 + k));
            acc[q].x = fmaf(xv.x, w0.x, acc[q].x); acc[q].y = fmaf(xv.x, w0.y, acc[q].y);
            acc[q].z = fmaf(xv.x, w0.z, acc[q].z); acc[q].w = fmaf(xv.x, w0.w, acc[q].w);
            acc[q].x = fmaf(xv.y, w1.x, acc[q].x); acc[q].y = fmaf(xv.y, w1.y, acc[q].y);
            acc[q].z = fmaf(xv.y, w1.z, acc[q].z); acc[q].w = fmaf(xv.y, w1.w, acc[q].w);
            acc[q].x = fmaf(xv.z, w2.x, acc[q].x); acc[q].y = fmaf(xv.z, w2.y, acc[q].y);
            acc[q].z = fmaf(xv.z, w2.z, acc[q].z); acc[q].w = fmaf(xv.z, w2.w, acc[q].w);
            acc[q].x = fmaf(xv.w, w3.x, acc[q].x); acc[q].y = fmaf(xv.w, w3.y, acc[q].y);
            acc[q].z = fmaf(xv.w, w3.z, acc[q].z); acc[q].w = fmaf(xv.w, w3.w, acc[q].w);
        }
    }

#pragma unroll
    for (int q = 0; q < 8; ++q) {
        int gr = r0 + ty * 8 + q;
        if (gr < nrows) {
            us4 o;
            o[0] = f2bf(acc[q].x); o[1] = f2bf(acc[q].y);
            o[2] = f2bf(acc[q].z); o[3] = f2bf(acc[q].w);
            *(us4*)(out + (size_t)gr * 128 + tx * 4) = o;
        }
    }
}

// ---- pull aggregation (bf16 gather, fp32 acc) + self-loop + bias [+relu], bf16 out ----
template <bool RELU>
__global__ __launch_bounds__(256) void k_agg(const int* __restrict__ cnt,
                                             const unsigned short* __restrict__ slot,
                                             const float* __restrict__ dis,
                                             const unsigned* __restrict__ hW,   // bf16x2 rows
                                             const float* __restrict__ b,
                                             unsigned* __restrict__ out) {      // bf16x2 rows
    int n = blockIdx.x * 4 + (threadIdx.x >> 6);
    int lane = threadIdx.x & 63;
    if (n >= NN) return;
    int c = cnt[n];
    if (c > CAP) c = CAP;
    float dn = dis[n];
    const unsigned short* sl = slot + (size_t)n * CAP;
    float a0 = 0.f, a1 = 0.f;
    int j = 0;
    for (; j + 7 < c; j += 8) {  // 8 gathers in flight
        us4 sa = *(const us4*)(sl + j);
        us4 sb = *(const us4*)(sl + j + 4);
        int s0 = sa[0], s1 = sa[1], s2 = sa[2], s3 = sa[3];
        int s4 = sb[0], s5 = sb[1], s6 = sb[2], s7 = sb[3];
        unsigned p0 = hW[(size_t)s0 * 64 + lane];
        unsigned p1 = hW[(size_t)s1 * 64 + lane];
        unsigned p2 = hW[(size_t)s2 * 64 + lane];
        unsigned p3 = hW[(size_t)s3 * 64 + lane];
        unsigned p4 = hW[(size_t)s4 * 64 + lane];
        unsigned p5 = hW[(size_t)s5 * 64 + lane];
        unsigned p6 = hW[(size_t)s6 * 64 + lane];
        unsigned p7 = hW[(size_t)s7 * 64 + lane];
        float nm0 = dn * dis[s0], nm1 = dn * dis[s1];
        float nm2 = dn * dis[s2], nm3 = dn * dis[s3];
        float nm4 = dn * dis[s4], nm5 = dn * dis[s5];
        float nm6 = dn * dis[s6], nm7 = dn * dis[s7];
        a0 = fmaf(bf_lo(p0), nm0, a0); a1 = fmaf(bf_hi(p0), nm0, a1);
        a0 = fmaf(bf_lo(p1), nm1, a0); a1 = fmaf(bf_hi(p1), nm1, a1);
        a0 = fmaf(bf_lo(p2), nm2, a0); a1 = fmaf(bf_hi(p2), nm2, a1);
        a0 = fmaf(bf_lo(p3), nm3, a0); a1 = fmaf(bf_hi(p3), nm3, a1);
        a0 = fmaf(bf_lo(p4), nm4, a0); a1 = fmaf(bf_hi(p4), nm4, a1);
        a0 = fmaf(bf_lo(p5), nm5, a0); a1 = fmaf(bf_hi(p5), nm5, a1);
        a0 = fmaf(bf_lo(p6), nm6, a0); a1 = fmaf(bf_hi(p6), nm6, a1);
        a0 = fmaf(bf_lo(p7), nm7, a0); a1 = fmaf(bf_hi(p7), nm7, a1);
    }
    for (; j + 3 < c; j += 4) {
        us4 sa = *(const us4*)(sl + j);
        int s0 = sa[0], s1 = sa[1], s2 = sa[2], s3 = sa[3];
        unsigned p0 = hW[(size_t)s0 * 64 + lane];
        unsigned p1 = hW[(size_t)s1 * 64 + lane];
        unsigned p2 = hW[(size_t)s2 * 64 + lane];
        unsigned p3 = hW[(size_t)s3 * 64 + lane];
        float nm0 = dn * dis[s0], nm1 = dn * dis[s1];
        float nm2 = dn * dis[s2], nm3 = dn * dis[s3];
        a0 = fmaf(bf_lo(p0), nm0, a0); a1 = fmaf(bf_hi(p0), nm0, a1);
        a0 = fmaf(bf_lo(p1), nm1, a0); a1 = fmaf(bf_hi(p1), nm1, a1);
        a0 = fmaf(bf_lo(p2), nm2, a0); a1 = fmaf(bf_hi(p2), nm2, a1);
        a0 = fmaf(bf_lo(p3), nm3, a0); a1 = fmaf(bf_hi(p3), nm3, a1);
    }
    for (; j < c; ++j) {
        int s0 = sl[j];
        unsigned p0 = hW[(size_t)s0 * 64 + lane];
        float nm0 = dn * dis[s0];
        a0 = fmaf(bf_lo(p0), nm0, a0); a1 = fmaf(bf_hi(p0), nm0, a1);
    }
    unsigned pn = hW[(size_t)n * 64 + lane];
    float r0 = fmaf(bf_lo(pn), dn * dn, a0) + b[2 * lane];
    float r1 = fmaf(bf_hi(pn), dn * dn, a1) + b[2 * lane + 1];
    if (RELU) {
        r0 = fmaxf(r0, 0.f);
        r1 = fmaxf(r1, 0.f);
    }
    out[(size_t)n * 64 + lane] = (unsigned)f2bf(r0) | ((unsigned)f2bf(r1) << 16);
}

// ---- decode tile compute (R4-verified): stage1 MFMA -> H overlay -> stage2 -> out ----
__device__ __forceinline__ void decode_tile(short* Fb, int qt, int w, int lr, int lk,
                                            const unsigned short* __restrict__ W1t,
                                            const float* __restrict__ db1,
                                            const unsigned short* __restrict__ W2t,
                                            const float* __restrict__ db2,
                                            float* __restrict__ out) {
    // stage 1: H = relu(F @ dW1 + db1); wave w owns cols [32w, 32w+32)
    f32x4 acc[4][2];
#pragma unroll
    for (int i = 0; i < 4; ++i)
#pragma unroll
        for (int j = 0; j < 2; ++j) acc[i][j] = (f32x4){0.f, 0.f, 0.f, 0.f};

    for (int ks = 0; ks < 8; ++ks) {
        int k8 = ks * 4 + lk;
        short8 a[4];
#pragma unroll
        for (int rt = 0; rt < 4; ++rt) {
            int row = rt * 16 + lr;
            a[rt] = *(const short8*)&Fb[row * 256 + (k8 ^ (row & 7)) * 8];
        }
#pragma unroll
        for (int cc = 0; cc < 2; ++cc) {
            int col = (2 * w + cc) * 16 + lr;
            short8 bfrag = *(const short8*)(W1t + col * 256 + ks * 32 + lk * 8);
#pragma unroll
            for (int rt = 0; rt < 4; ++rt)
                acc[rt][cc] = __builtin_amdgcn_mfma_f32_16x16x32_bf16(a[rt], bfrag, acc[rt][cc], 0, 0, 0);
        }
    }
    __syncthreads();  // all waves done reading Fb before Hb overlay writes

#pragma unroll
    for (int cc = 0; cc < 2; ++cc) {
        int col = (2 * w + cc) * 16 + lr;
        float bv = db1[col];
#pragma unroll
        for (int rt = 0; rt < 4; ++rt) {
#pragma unroll
            for (int r = 0; r < 4; ++r) {
                int row = rt * 16 + lk * 4 + r;  // C: row=(lane>>4)*4+reg, col=lane&15
                float hv = fmaxf(acc[rt][cc][r] + bv, 0.f);
                Fb[row * 128 + ((col >> 3) ^ (row & 7)) * 8 + (col & 7)] = (short)f2bf(hv);
            }
        }
    }
    __syncthreads();

    // stage 2: out = H @ dW2 + db2; wave w owns rows [16w, 16w+16)
    f32x4 acc2[6];
#pragma unroll
    for (int i = 0; i < 6; ++i) acc2[i] = (f32x4){0.f, 0.f, 0.f, 0.f};
    for (int ks = 0; ks < 4; ++ks) {
        int row = w * 16 + lr;
        int k8 = ks * 4 + lk;
        short8 a = *(const short8*)&Fb[row * 128 + (k8 ^ (row & 7)) * 8];
#pragma unroll
        for (int ct = 0; ct < 6; ++ct) {
            int col = ct * 16 + lr;
            short8 bfrag = *(const short8*)(W2t + col * 128 + ks * 32 + lk * 8);
            acc2[ct] = __builtin_amdgcn_mfma_f32_16x16x32_bf16(a, bfrag, acc2[ct], 0, 0, 0);
        }
    }
#pragma unroll
    for (int ct = 0; ct < 6; ++ct) {
        int c = ct * 16 + lr;
        if (c < NC) {
            float bv = db2[c];
#pragma unroll
            for (int r = 0; r < 4; ++r) {
                int q = qt + w * 16 + lk * 4 + r;
                out[(size_t)q * NC + c] = acc2[ct][r] + bv;
            }
        }
    }
}

// ---- decode: 2 tiles of 64 queries per block; tile1 gathers issued to registers
// ---- before tile0 compute (T14 async-STAGE) so HBM latency hides under MFMA.
__global__ __launch_bounds__(256) void k_decode(const int* __restrict__ eli,
                                                const unsigned short* __restrict__ z,
                                                const unsigned short* __restrict__ W1t,
                                                const float* __restrict__ db1,
                                                const unsigned short* __restrict__ W2t,
                                                const float* __restrict__ db2,
                                                float* __restrict__ out) {
    __shared__ short Fb[64 * 256];  // 32 KB; H overlays first 16 KB per tile
    const int t = threadIdx.x;
    const int w = t >> 6;
    const int lane = t & 63;
    const int lr = lane & 15;
    const int lk = lane >> 4;
    const int q0 = blockIdx.x * 128;
    const bool has2 = (q0 + 64) < NQ;  // block-uniform (3125 tiles, odd)

    // ---- stage tile0 directly to LDS ----
#pragma unroll
    for (int it = 0; it < 8; ++it) {
        int g = it * 256 + t;  // 64 rows x 32 granules of 8 bf16
        int row = g >> 5, k8 = g & 31;
        int q = q0 + row;
        int node = (k8 < 16) ? eli[q] : eli[q + NQ];
        short8 v = *(const short8*)(z + (size_t)node * 128 + (k8 & 15) * 8);
        *(short8*)&Fb[row * 256 + (k8 ^ (row & 7)) * 8] = v;
    }
    __syncthreads();

    // ---- issue tile1 gathers into registers (drain under tile0 compute) ----
    short8 pre[8];
    if (has2) {
#pragma unroll
        for (int it = 0; it < 8; ++it) {
            int g = it * 256 + t;
            int row = g >> 5, k8 = g & 31;
            int q = q0 + 64 + row;
            int node = (k8 < 16) ? eli[q] : eli[q + NQ];
            pre[it] = *(const short8*)(z + (size_t)node * 128 + (k8 & 15) * 8);
        }
    }

    decode_tile(Fb, q0, w, lr, lk, W1t, db1, W2t, db2, out);

    if (has2) {
        __syncthreads();  // all waves done reading H/Fb of tile0
#pragma unroll
        for (int it = 0; it < 8; ++it) {
            int g = it * 256 + t;
            int row = g >> 5, k8 = g & 31;
            *(short8*)&Fb[row * 256 + (k8 ^ (row & 7)) * 8] = pre[it];
        }
        __syncthreads();
        decode_tile(Fb, q0 + 64, w, lr, lk, W1t, db1, W2t, db2, out);
    }
}

extern "C" void kernel_launch(void* const* d_in, const int* in_sizes, int n_in,
                              void* d_out, int out_size, void* d_ws, size_t ws_size,
                              hipStream_t stream) {
    const int* x = (const int*)d_in[0];
    const int* ei = (const int*)d_in[1];
    const int* eli = (const int*)d_in[2];
    const float* emb = (const float*)d_in[3];
    const float* W1 = (const float*)d_in[4];
    const float* b1 = (const float*)d_in[5];
    const float* W2 = (const float*)d_in[6];
    const float* b2 = (const float*)d_in[7];
    const float* dW1 = (const float*)d_in[8];
    const float* db1 = (const float*)d_in[9];
    const float* dW2 = (const float*)d_in[10];
    const float* db2 = (const float*)d_in[11];
    float* out = (float*)d_out;

    const int* src = ei;
    const int* dst = ei + NE;

    unsigned short* hA = (unsigned short*)d_ws;          // NN*128 bf16
    unsigned short* hB = hA + (size_t)NN * 128;          // NN*128 bf16
    int* cnt = (int*)(hB + (size_t)NN * 128);            // NN
    float* dis = (float*)(cnt + NN);                     // NN
    unsigned short* slot = (unsigned short*)(dis + NN);  // NN*CAP u16
    unsigned short* W1t = slot + (size_t)NN * CAP;       // 128*256
    unsigned short* W2t = W1t + 128 * 256;               // 96*128

    hipMemsetAsync(cnt, 0, NN * sizeof(int), stream);
    k_prep<<<128, 256, 0, stream>>>(dW1, dW2, W1t, W2t);
    k_fill<<<(NE + 255) / 256, 256, 0, stream>>>(src, dst, cnt, slot);
    k_dis<<<(NN + 255) / 256, 256, 0, stream>>>(cnt, dis);

    // layer 1: hA = emb@W1 (bf16); hB = relu(agg(hA)+b1) (bf16)
    k_linear<true, false><<<(NN + 63) / 64, 256, 0, stream>>>(emb, x, W1, hA, NN);
    k_agg<true><<<NN / 4, 256, 0, stream>>>(cnt, slot, dis, (const unsigned*)hA, b1,
                                            (unsigned*)hB);

    // layer 2: hA = hB@W2 (bf16); hB = agg(hA)+b2 = z (bf16)
    k_linear<false, true><<<(NN + 63) / 64, 256, 0, stream>>>(hB, nullptr, W2, hA, NN);
    k_agg<false><<<NN / 4, 256, 0, stream>>>(cnt, slot, dis, (const unsigned*)hA, b2,
                                             (unsigned*)hB);

    // decode: 2 tiles/block
    k_decode<<<(NQ / 64 + 1) / 2, 256, 0, stream>>>(eli, hB, W1t, db1, W2t, db2, out);
}

// Round 9
// 365.839 us; speedup vs baseline: 1.1746x; 1.0215x over previous
//
#include <hip/hip_runtime.h>

#define NN 50000
#define NE 800000
#define NQ 200000
#define NC 86
#define CAP 64

typedef short short8 __attribute__((ext_vector_type(8)));
typedef float f32x4 __attribute__((ext_vector_type(4)));
typedef unsigned short us4 __attribute__((ext_vector_type(4)));

__device__ __forceinline__ unsigned short f2bf(float f) {
    unsigned u = __float_as_uint(f);
    u += 0x7FFF + ((u >> 16) & 1);  // round-to-nearest-even
    return (unsigned short)(u >> 16);
}
__device__ __forceinline__ float bf_lo(unsigned p) { return __uint_as_float(p << 16); }
__device__ __forceinline__ float bf_hi(unsigned p) { return __uint_as_float(p & 0xffff0000u); }

// ---------------- CSR build: slot[dst][p] = src (atomic append) ----------------
__global__ __launch_bounds__(256) void k_fill(const int* __restrict__ src,
                                              const int* __restrict__ dst,
                                              int* __restrict__ cnt,
                                              unsigned short* __restrict__ slot) {
    int e = blockIdx.x * 256 + threadIdx.x;
    if (e >= NE) return;
    int d = dst[e];
    int p = atomicAdd(&cnt[d], 1);
    if (p < CAP) slot[(size_t)d * CAP + p] = (unsigned short)src[e];
}

__global__ __launch_bounds__(256) void k_dis(const int* __restrict__ cnt,
                                             float* __restrict__ dis) {
    int n = blockIdx.x * 256 + threadIdx.x;
    if (n < NN) dis[n] = rsqrtf((float)cnt[n] + 1.0f);
}

// ------- weight prep: decode W^T (W1t,W2t) + conv W^T (W1c,W2c), all bf16 -------
__global__ __launch_bounds__(256) void k_prep(const float* __restrict__ dW1,
                                              const float* __restrict__ dW2,
                                              const float* __restrict__ W1,
                                              const float* __restrict__ W2,
                                              unsigned short* __restrict__ W1t,
                                              unsigned short* __restrict__ W2t,
                                              unsigned short* __restrict__ W1c,
                                              unsigned short* __restrict__ W2c) {
    int i = blockIdx.x * 256 + threadIdx.x;
    if (i < 128 * 256) {  // W1t[col][k] = dW1[k][col]
        int c = i >> 8, k = i & 255;
        W1t[c * 256 + k] = f2bf(dW1[k * 128 + c]);
    }
    if (i < 96 * 128) {   // W2t[col][k] = dW2[k][col], cols padded 86->96
        int c = i >> 7, k = i & 127;
        W2t[c * 128 + k] = (c < NC) ? f2bf(dW2[k * NC + c]) : (unsigned short)0;
    }
    if (i < 128 * 128) {  // conv weights transposed
        int c = i >> 7, k = i & 127;
        W1c[c * 128 + k] = f2bf(W1[k * 128 + c]);
        W2c[c * 128 + k] = f2bf(W2[k * 128 + c]);
    }
}

// ------- X @ W via bf16 MFMA (transposed: H^T = W^T * X^T), out bf16 -------
// Wt: bf16 W^T [128][128] (row c = W[:,c]), 32 KB, L1-resident.
template <bool GATHER, bool BF16IN>
__global__ __launch_bounds__(256) void k_linear(const void* __restrict__ Xv,
                                                const int* __restrict__ xidx,
                                                const unsigned short* __restrict__ Wt,
                                                unsigned short* __restrict__ out,
                                                int nrows) {
    __shared__ short Xb[64 * 128];  // 16 KB bf16, XOR-swizzled 16B granules
    const int t = threadIdx.x;
    const int r0 = blockIdx.x * 64;

#pragma unroll
    for (int it = 0; it < 4; ++it) {
        int g = it * 256 + t;  // 64 rows x 16 granules of 8 bf16
        int row = g >> 4, g8 = g & 15;
        int node = r0 + row;
        short8 v = (short8){0, 0, 0, 0, 0, 0, 0, 0};
        if (node < nrows) {
            int sr = GATHER ? xidx[node] : node;
            if (BF16IN) {
                v = *(const short8*)((const unsigned short*)Xv + (size_t)sr * 128 + g8 * 8);
            } else {
                const float* p = (const float*)Xv + (size_t)sr * 128 + g8 * 8;
                float4 f0 = ((const float4*)p)[0];
                float4 f1 = ((const float4*)p)[1];
                v[0] = (short)f2bf(f0.x); v[1] = (short)f2bf(f0.y);
                v[2] = (short)f2bf(f0.z); v[3] = (short)f2bf(f0.w);
                v[4] = (short)f2bf(f1.x); v[5] = (short)f2bf(f1.y);
                v[6] = (short)f2bf(f1.z); v[7] = (short)f2bf(f1.w);
            }
        }
        *(short8*)&Xb[row * 128 + ((g8 ^ (row & 7)) * 8)] = v;
    }
    __syncthreads();

    const int w = t >> 6;
    const int lane = t & 63;
    const int lr = lane & 15;
    const int lk = lane >> 4;
    const int qrow = w * 16 + lr;  // X row within tile (B-operand column)

    f32x4 acc[8];
#pragma unroll
    for (int i = 0; i < 8; ++i) acc[i] = (f32x4){0.f, 0.f, 0.f, 0.f};

    for (int ks = 0; ks < 4; ++ks) {
        int k8 = ks * 4 + lk;
        short8 b = *(const short8*)&Xb[qrow * 128 + ((k8 ^ (qrow & 7)) * 8)];
#pragma unroll
        for (int ct = 0; ct < 8; ++ct) {
            short8 a = *(const short8*)(Wt + (size_t)(ct * 16 + lr) * 128 + k8 * 8);
            acc[ct] = __builtin_amdgcn_mfma_f32_16x16x32_bf16(a, b, acc[ct], 0, 0, 0);
        }
    }

    // C layout: col(lr) = q-in-tile, row(lk*4+r) = W-output-col -> 4 consecutive feats
    int q = r0 + w * 16 + lr;
    if (q < nrows) {
#pragma unroll
        for (int ct = 0; ct < 8; ++ct) {
            us4 o;
            o[0] = f2bf(acc[ct][0]); o[1] = f2bf(acc[ct][1]);
            o[2] = f2bf(acc[ct][2]); o[3] = f2bf(acc[ct][3]);
            *(us4*)(out + (size_t)q * 128 + ct * 16 + lk * 4) = o;
        }
    }
}

// ---- pull aggregation: 2 edges per wave-instruction (8B/lane), fp32 acc ----
// lane = (half, li): half picks even/odd edge, li covers features 4li..4li+3.
template <bool RELU>
__global__ __launch_bounds__(256) void k_agg(const int* __restrict__ cnt,
                                             const unsigned short* __restrict__ slot,
                                             const float* __restrict__ dis,
                                             const unsigned* __restrict__ hW,   // bf16x2 rows
                                             const float* __restrict__ b,
                                             unsigned* __restrict__ out) {      // bf16x2 rows
    int n = blockIdx.x * 4 + (threadIdx.x >> 6);
    int lane = threadIdx.x & 63;
    int half = lane >> 5, li = lane & 31;
    if (n >= NN) return;
    int c = cnt[n];
    if (c > CAP) c = CAP;
    float dn = dis[n];
    int sv = slot[(size_t)n * CAP + lane];  // coalesced slot row; broadcast via shfl

    float a0 = 0.f, a1 = 0.f, a2 = 0.f, a3 = 0.f;
    for (int j = 0; j < c; j += 16) {  // 16 edges per iteration (8 per half)
        int s[8];
        float nm[8];
#pragma unroll
        for (int k = 0; k < 8; ++k) {
            int e = j + 2 * k + half;
            int sk = __shfl(sv, e & 63);
            bool ok = e < c;
            s[k] = ok ? sk : 0;
            nm[k] = ok ? 1.0f : 0.0f;
        }
        uint2 p[8];
#pragma unroll
        for (int k = 0; k < 8; ++k)
            p[k] = *(const uint2*)(hW + (size_t)s[k] * 64 + 2 * li);
#pragma unroll
        for (int k = 0; k < 8; ++k) nm[k] *= dn * dis[s[k]];
#pragma unroll
        for (int k = 0; k < 8; ++k) {
            a0 = fmaf(bf_lo(p[k].x), nm[k], a0);
            a1 = fmaf(bf_hi(p[k].x), nm[k], a1);
            a2 = fmaf(bf_lo(p[k].y), nm[k], a2);
            a3 = fmaf(bf_hi(p[k].y), nm[k], a3);
        }
    }
    // merge the two halves
    a0 += __shfl_xor(a0, 32);
    a1 += __shfl_xor(a1, 32);
    a2 += __shfl_xor(a2, 32);
    a3 += __shfl_xor(a3, 32);

    if (half == 0) {
        uint2 pn = *(const uint2*)(hW + (size_t)n * 64 + 2 * li);
        float d2 = dn * dn;
        float4 bb = *(const float4*)(b + 4 * li);
        float r0 = fmaf(bf_lo(pn.x), d2, a0) + bb.x;
        float r1 = fmaf(bf_hi(pn.x), d2, a1) + bb.y;
        float r2 = fmaf(bf_lo(pn.y), d2, a2) + bb.z;
        float r3 = fmaf(bf_hi(pn.y), d2, a3) + bb.w;
        if (RELU) {
            r0 = fmaxf(r0, 0.f); r1 = fmaxf(r1, 0.f);
            r2 = fmaxf(r2, 0.f); r3 = fmaxf(r3, 0.f);
        }
        uint2 o;
        o.x = (unsigned)f2bf(r0) | ((unsigned)f2bf(r1) << 16);
        o.y = (unsigned)f2bf(r2) | ((unsigned)f2bf(r3) << 16);
        *(uint2*)(out + (size_t)n * 64 + 2 * li) = o;
    }
}

// ------------- decode (R4-verified, 81 us): z bf16; Hb overlays Fb (32 KB LDS) -------------
__global__ __launch_bounds__(256) void k_decode(const int* __restrict__ eli,
                                                const unsigned short* __restrict__ z,
                                                const unsigned short* __restrict__ W1t,
                                                const float* __restrict__ db1,
                                                const unsigned short* __restrict__ W2t,
                                                const float* __restrict__ db2,
                                                float* __restrict__ out) {
    __shared__ short Fb[64 * 256];  // 32 KB; Hb (64x128) overlays the same storage
    const int t = threadIdx.x;
    const int q0 = blockIdx.x * 64;
    const int lane = t & 63;
    const int w = t >> 6;
    const int lr = lane & 15;
    const int lk = lane >> 4;

    // ---- stage F tile: row q -> [z_u | z_v] (bf16 passthrough), swizzled ----
#pragma unroll
    for (int it = 0; it < 8; ++it) {
        int g = it * 256 + t;  // 64 rows x 32 granules of 8 bf16
        int row = g >> 5, k8 = g & 31;
        int q = q0 + row;
        int node = (k8 < 16) ? eli[q] : eli[q + NQ];
        short8 v = *(const short8*)(z + (size_t)node * 128 + (k8 & 15) * 8);
        *(short8*)&Fb[row * 256 + (k8 ^ (row & 7)) * 8] = v;
    }
    __syncthreads();

    // ---- stage 1: H = relu(F @ dW1 + db1); wave w owns cols [32w, 32w+32) ----
    f32x4 acc[4][2];
#pragma unroll
    for (int i = 0; i < 4; ++i)
#pragma unroll
        for (int j = 0; j < 2; ++j) acc[i][j] = (f32x4){0.f, 0.f, 0.f, 0.f};

    for (int ks = 0; ks < 8; ++ks) {
        int k8 = ks * 4 + lk;
        short8 a[4];
#pragma unroll
        for (int rt = 0; rt < 4; ++rt) {
            int row = rt * 16 + lr;
            a[rt] = *(const short8*)&Fb[row * 256 + (k8 ^ (row & 7)) * 8];
        }
#pragma unroll
        for (int cc = 0; cc < 2; ++cc) {
            int col = (2 * w + cc) * 16 + lr;
            short8 bfrag = *(const short8*)(W1t + col * 256 + ks * 32 + lk * 8);
#pragma unroll
            for (int rt = 0; rt < 4; ++rt)
                acc[rt][cc] = __builtin_amdgcn_mfma_f32_16x16x32_bf16(a[rt], bfrag, acc[rt][cc], 0, 0, 0);
        }
    }
    __syncthreads();  // all waves done reading Fb before Hb overlay writes

#pragma unroll
    for (int cc = 0; cc < 2; ++cc) {
        int col = (2 * w + cc) * 16 + lr;
        float bv = db1[col];
#pragma unroll
        for (int rt = 0; rt < 4; ++rt) {
#pragma unroll
            for (int r = 0; r < 4; ++r) {
                int row = rt * 16 + lk * 4 + r;  // C: row=(lane>>4)*4+reg, col=lane&15
                float hv = fmaxf(acc[rt][cc][r] + bv, 0.f);
                Fb[row * 128 + ((col >> 3) ^ (row & 7)) * 8 + (col & 7)] = (short)f2bf(hv);
            }
        }
    }
    __syncthreads();

    // ---- stage 2: out = H @ dW2 + db2; wave w owns rows [16w, 16w+16) ----
    f32x4 acc2[6];
#pragma unroll
    for (int i = 0; i < 6; ++i) acc2[i] = (f32x4){0.f, 0.f, 0.f, 0.f};
    for (int ks = 0; ks < 4; ++ks) {
        int row = w * 16 + lr;
        int k8 = ks * 4 + lk;
        short8 a = *(const short8*)&Fb[row * 128 + (k8 ^ (row & 7)) * 8];
#pragma unroll
        for (int ct = 0; ct < 6; ++ct) {
            int col = ct * 16 + lr;
            short8 bfrag = *(const short8*)(W2t + col * 128 + ks * 32 + lk * 8);
            acc2[ct] = __builtin_amdgcn_mfma_f32_16x16x32_bf16(a, bfrag, acc2[ct], 0, 0, 0);
        }
    }
#pragma unroll
    for (int ct = 0; ct < 6; ++ct) {
        int c = ct * 16 + lr;
        if (c < NC) {
            float bv = db2[c];
#pragma unroll
            for (int r = 0; r < 4; ++r) {
                int q = q0 + w * 16 + lk * 4 + r;
                out[(size_t)q * NC + c] = acc2[ct][r] + bv;
            }
        }
    }
}

extern "C" void kernel_launch(void* const* d_in, const int* in_sizes, int n_in,
                              void* d_out, int out_size, void* d_ws, size_t ws_size,
                              hipStream_t stream) {
    const int* x = (const int*)d_in[0];
    const int* ei = (const int*)d_in[1];
    const int* eli = (const int*)d_in[2];
    const float* emb = (const float*)d_in[3];
    const float* W1 = (const float*)d_in[4];
    const float* b1 = (const float*)d_in[5];
    const float* W2 = (const float*)d_in[6];
    const float* b2 = (const float*)d_in[7];
    const float* dW1 = (const float*)d_in[8];
    const float* db1 = (const float*)d_in[9];
    const float* dW2 = (const float*)d_in[10];
    const float* db2 = (const float*)d_in[11];
    float* out = (float*)d_out;

    const int* src = ei;
    const int* dst = ei + NE;

    unsigned short* hA = (unsigned short*)d_ws;          // NN*128 bf16
    unsigned short* hB = hA + (size_t)NN * 128;          // NN*128 bf16
    int* cnt = (int*)(hB + (size_t)NN * 128);            // NN
    float* dis = (float*)(cnt + NN);                     // NN
    unsigned short* slot = (unsigned short*)(dis + NN);  // NN*CAP u16 (+64 slack)
    unsigned short* W1t = slot + (size_t)NN * CAP + 64;  // 128*256
    unsigned short* W2t = W1t + 128 * 256;               // 96*128
    unsigned short* W1c = W2t + 96 * 128;                // 128*128
    unsigned short* W2c = W1c + 128 * 128;               // 128*128

    hipMemsetAsync(cnt, 0, NN * sizeof(int), stream);
    k_prep<<<128, 256, 0, stream>>>(dW1, dW2, W1, W2, W1t, W2t, W1c, W2c);
    k_fill<<<(NE + 255) / 256, 256, 0, stream>>>(src, dst, cnt, slot);
    k_dis<<<(NN + 255) / 256, 256, 0, stream>>>(cnt, dis);

    // layer 1: hA = emb@W1 (bf16 MFMA); hB = relu(agg(hA)+b1) (bf16)
    k_linear<true, false><<<(NN + 63) / 64, 256, 0, stream>>>(emb, x, W1c, hA, NN);
    k_agg<true><<<NN / 4, 256, 0, stream>>>(cnt, slot, dis, (const unsigned*)hA, b1,
                                            (unsigned*)hB);

    // layer 2: hA = hB@W2 (bf16 MFMA); hB = agg(hA)+b2 = z (bf16)
    k_linear<false, true><<<(NN + 63) / 64, 256, 0, stream>>>(hB, nullptr, W2c, hA, NN);
    k_agg<false><<<NN / 4, 256, 0, stream>>>(cnt, slot, dis, (const unsigned*)hA, b2,
                                             (unsigned*)hB);

    // decode (R4 structure, 1 tile of 64 queries per block)
    k_decode<<<NQ / 64, 256, 0, stream>>>(eli, hB, W1t, db1, W2t, db2, out);
}